// Round 4
// baseline (265.426 us; speedup 1.0000x reference)
//
#include <hip/hip_runtime.h>

#define PI_F 3.14159265358979323846f

constexpr int N_COLS = 16384;   // row length
constexpr int HALF   = 8192;    // N/2 : half-size complex FFT length
constexpr int NT     = 1024;

// Bank swizzle: XOR-folds addr bits 3..7 and 8..12 into bits 0..4.
// Bijective on [0,8192). GF(2) span analysis per access pattern:
//   pass A/B (lane bits at a0..a5), pass C (j at a0..a3, subgroup at a7..a8),
//   pass D (j at a0, h at a4..a8) -> all 2-way (free).
//   epilogue (u at a7,a10..a12 + 13-bit complement pairs) -> 4-way residual.
// Note bit 0 is not a fold source, so swz(a^1) = swz(a)^1.
__device__ __forceinline__ int swz(int a) {
    return a ^ ((a >> 3) & 31) ^ ((a >> 8) & 31);
}

// Radix-8 inverse-DFT butterfly (positive exponent) + external twiddles:
// out[i] = T^i * sum_r W8^{ir} v[r],  T=(ct,st), W8 = e^{+j*2pi/8}.
__device__ __forceinline__ void bfly8_tw(float (&vr)[8], float (&vi)[8],
                                         float ct, float st)
{
    const float RS = 0.70710678118654752f;
    // even DFT4 (inverse): A1 = e1 + j e3, A3 = e1 - j e3
    float e0r = vr[0]+vr[4], e0i = vi[0]+vi[4];
    float e1r = vr[0]-vr[4], e1i = vi[0]-vi[4];
    float e2r = vr[2]+vr[6], e2i = vi[2]+vi[6];
    float e3r = vr[2]-vr[6], e3i = vi[2]-vi[6];
    float A0r = e0r+e2r, A0i = e0i+e2i;
    float A2r = e0r-e2r, A2i = e0i-e2i;
    float A1r = e1r-e3i, A1i = e1i+e3r;
    float A3r = e1r+e3i, A3i = e1i-e3r;
    // odd DFT4
    float o0r = vr[1]+vr[5], o0i = vi[1]+vi[5];
    float o1r = vr[1]-vr[5], o1i = vi[1]-vi[5];
    float o2r = vr[3]+vr[7], o2i = vi[3]+vi[7];
    float o3r = vr[3]-vr[7], o3i = vi[3]-vi[7];
    float B0r = o0r+o2r, B0i = o0i+o2i;
    float B2r = o0r-o2r, B2i = o0i-o2i;
    float B1r = o1r-o3i, B1i = o1i+o3r;
    float B3r = o1r+o3i, B3i = o1i-o3r;
    // W8 internal twiddles (inverse): B1*=(RS+jRS), B2*=j, B3*=(-RS+jRS)
    float t;
    t = RS*(B1r - B1i); B1i = RS*(B1r + B1i); B1r = t;
    t = -B2i;           B2i = B2r;            B2r = t;
    t = -RS*(B3r + B3i); B3i = RS*(B3r - B3i); B3r = t;
    // combine u_i = A_i + B_i ; u_{i+4} = A_i - B_i
    vr[0]=A0r+B0r; vi[0]=A0i+B0i;  vr[4]=A0r-B0r; vi[4]=A0i-B0i;
    vr[1]=A1r+B1r; vi[1]=A1i+B1i;  vr[5]=A1r-B1r; vi[5]=A1i-B1i;
    vr[2]=A2r+B2r; vi[2]=A2i+B2i;  vr[6]=A2r-B2r; vi[6]=A2i-B2i;
    vr[3]=A3r+B3r; vi[3]=A3i+B3i;  vr[7]=A3r-B3r; vi[7]=A3i-B3i;
    // external twiddles: progressive powers of T
    float wr = ct, wi = st;
    #pragma unroll
    for (int i = 1; i < 8; ++i) {
        float xr2 = vr[i]*wr - vi[i]*wi;
        float xi2 = vr[i]*wi + vi[i]*wr;
        vr[i] = xr2; vi[i] = xi2;
        if (i < 7) { float nr = wr*ct - wi*st, ni = wr*st + wi*ct; wr = nr; wi = ni; }
    }
}

// One DIF pass over LDS, stride S (sub-block length 8S), in-place.
// sdata[0..HALF) = re, sdata[HALF..2*HALF) = im.
template<int S>
__device__ __forceinline__ void lds_pass(float* sdata, int b)
{
    const int j = b & (S - 1);
    const int base = ((b & ~(S - 1)) << 3) + j;   // g*8S + j
    int pa[8];
    float vr[8], vi[8];
    #pragma unroll
    for (int r = 0; r < 8; ++r) {
        pa[r] = swz(base + S * r);
        vr[r] = sdata[pa[r]];
        vi[r] = sdata[HALF + pa[r]];
    }
    float st, ct;
    __sincosf((float)j * (PI_F / (4.0f * (float)S)), &st, &ct);  // 2pi*j/(8S)
    bfly8_tw(vr, vi, ct, st);
    #pragma unroll
    for (int i = 0; i < 8; ++i) {
        sdata[pa[i]]        = vr[i];
        sdata[HALF + pa[i]] = vi[i];
    }
}

// One block per row.
//   V_k = (x_k - j x_{N-k}) e^{j pi k/(2N)};  Z_k = (V_k+V_{k+H}) + j e^{j2pik/N}(V_k-V_{k+H})
//   8192-pt inverse DFT of Z via DIF: radix-8 in registers (stride 1024, reg-resident)
//   + 3 LDS radix-8 passes (128, 16, 2) + radix-2 fused into epilogue.
//   Output position of frequency m: digit-reverse pe = (m&7)<<10 | ... | ((m>>9)&7)<<1,
//   pair {pe, pe+1}, z_m = v(pe) +/- v(pe+1) by bit m>>12.
__global__ __launch_bounds__(NT, 8)
void idxct_kernel(const float* __restrict__ x,
                  const float* __restrict__ expk,
                  float* __restrict__ y)
{
    __shared__ float sdata[2 * HALF];

    const int row = blockIdx.x;
    const float* __restrict__ xr = x + (size_t)row * N_COLS;
    float* __restrict__ yrp      = y + (size_t)row * N_COLS;
    const int b = threadIdx.x;
    const float x0 = xr[0];
    const float2* __restrict__ ek2 = (const float2*)expk;

    float vr[8], vi[8];

    // ---- preprocess: Z_k in registers, k = b + 1024 r ----
    #pragma unroll
    for (int r = 0; r < 8; ++r) {
        int k = b + (r << 10);
        float2 e = ek2[k];
        float c0 = e.x, s0 = -e.y;             // e^{+j pi k/(2N)}
        int kb = (k == 0) ? 0 : (N_COLS - k);
        float a  = xr[k], bb = xr[kb];
        float vkr = a * c0 + bb * s0;          // (a - j b)(c + j s)
        float vki = a * s0 - bb * c0;
        if (k == 0) { vkr = x0; vki = 0.0f; }
        int K = k + HALF;
        float2 e2 = ek2[K];
        float c1 = e2.x, s1 = -e2.y;
        float aa = xr[K], b2 = xr[N_COLS - K];
        float wkr = aa * c1 + b2 * s1;
        float wki = aa * s1 - b2 * c1;
        float dr = vkr - wkr, di = vki - wki;
        // e^{j 2 pi k / N} = (c0 + j s0)^4
        float cA = c0 * c0 - s0 * s0, sA = 2.0f * c0 * s0;
        float ec = cA * cA - sA * sA, es = 2.0f * cA * sA;
        vr[r] = (vkr + wkr) - (ec * di + es * dr);
        vi[r] = (vki + wki) + (ec * dr - es * di);
    }

    // ---- pass A: stride 1024, register-resident (j = b), write LDS ----
    {
        float st, ct;
        __sincosf((float)b * (PI_F / 4096.0f), &st, &ct);   // 2pi*b/8192
        bfly8_tw(vr, vi, ct, st);
        #pragma unroll
        for (int i = 0; i < 8; ++i) {
            int pa = swz(b + (i << 10));
            sdata[pa]        = vr[i];
            sdata[HALF + pa] = vi[i];
        }
    }

    __syncthreads();
    lds_pass<128>(sdata, b);
    __syncthreads();
    lds_pass<16>(sdata, b);
    __syncthreads();
    lds_pass<2>(sdata, b);
    __syncthreads();

    // ---- epilogue: fused final radix-2 + DCT post-twist, coalesced writes ----
    #pragma unroll
    for (int i = 0; i < 16; ++i) {
        int q = b + (i << 10);
        int qh = q >> 1;
        int pidx = (q & 1) ? (N_COLS - 1 - qh) : qh;
        int comp = (pidx & 1) << 13;           // select re/im plane
        int m = pidx >> 1;                     // frequency into z
        int j5 = m >> 12;
        int mm = m & 4095;
        int pe = ((mm & 7) << 10) | (((mm >> 3) & 7) << 7)
               | (((mm >> 6) & 7) << 4) | (((mm >> 9) & 7) << 1);
        int a0 = swz(pe);                      // swz(pe|1) == a0^1
        float v0 = sdata[comp + a0];
        float v1 = sdata[comp + (a0 ^ 1)];
        float val = j5 ? (v0 - v1) : (v0 + v1);
        yrp[q] = 0.5f * (val + x0);
    }
}

extern "C" void kernel_launch(void* const* d_in, const int* in_sizes, int n_in,
                              void* d_out, int out_size, void* d_ws, size_t ws_size,
                              hipStream_t stream)
{
    const float* x    = (const float*)d_in[0];
    const float* expk = (const float*)d_in[1];
    float* y          = (float*)d_out;
    const int M = in_sizes[0] / N_COLS;        // 2048 rows
    idxct_kernel<<<dim3(M), dim3(NT), 0, stream>>>(x, expk, y);
}